// Round 1
// 271.309 us; speedup vs baseline: 1.0903x; 1.0903x over previous
//
#include <hip/hip_runtime.h>
#include <hip/hip_bf16.h>
#include <hip/hip_fp16.h>
#include <math.h>

typedef unsigned int u32;
typedef unsigned short u16;

// f32 weight-blob offsets (in floats)
#define O_W1 0
#define O_b1 16384
#define O_W2 16512
#define O_b2 24704
#define O_W3 24768
#define O_b3 29056
#define O_P1 29123
#define O_pb1 31171
#define O_P2 31203
#define O_pb2 31235
#define W_TOTAL 31236

#define LDP 65   // LDS leading-dim pad for k3a-era layout (unused by new k3b)
#define NPB 16   // nodes per block in k3b (16 -> ~600+ working blocks at nmask~10k)
#define LDW 17   // node-dim pad (17 odd -> conflict-free strided LDS)

// dt codes: 0 = f32, 1 = bf16, 2 = f16
__device__ __forceinline__ float ldf(const void* p, long i, int dt) {
  if (dt == 1) { u32 v = ((const u16*)p)[i]; return __uint_as_float(v << 16); }
  if (dt == 2) { __half h = ((const __half*)p)[i]; return __half2float(h); }
  return ((const float*)p)[i];
}
__device__ __forceinline__ int ldei(const int* p, long i, int is64) {
  return is64 ? p[2 * i] : p[i];
}

// hdr: [0]=dt_feat [1]=dt_w [2]=ei is64 [3]=dt_ops [4]=masked count [5]=adj total
// ---------- merged detectors: block 0=feat,1=W1,2=ops,3=ei ----------
extern "C" __global__ void kall_detect(const u32* __restrict__ feat,
                                       const u32* __restrict__ w1,
                                       const u32* __restrict__ ops,
                                       const u32* __restrict__ ei,
                                       int* __restrict__ hdr)
{
  int lane = threadIdx.x;                 // 64 threads/block
  int mode = blockIdx.x;
  if (mode == 3) {                        // int64 edge check
    unsigned long long m0 = __ballot(ei[lane] == 0u);
    unsigned long long m1 = __ballot(ei[64 + lane] == 0u);
    if (lane == 0) hdr[2] = (__popcll(m0) + __popcll(m1) >= 32) ? 1 : 0;
    return;
  }
  const u32* p = (mode == 0) ? feat : (mode == 1) ? w1 : ops;
  int slot = (mode == 0) ? 0 : (mode == 1) ? 1 : 3;
  u32 w0 = p[lane];
  u32 w1v = p[64 + lane];
  u16 h[4] = { (u16)(w0 & 0xffff), (u16)(w0 >> 16),
               (u16)(w1v & 0xffff), (u16)(w1v >> 16) };
  int cb = 0;
#pragma unroll
  for (int t = 0; t < 4; ++t) {
    int e8 = (h[t] >> 7) & 0xff;
    cb += (e8 >= 110 && e8 <= 140) ? 1 : 0;
  }
  int ch = 0;                              // f16 check on EVEN u16s only
#pragma unroll
  for (int t = 0; t < 4; t += 2) {
    int e5 = (h[t] >> 10) & 0x1f;
    ch += (e5 >= 5 && e5 <= 18) ? 1 : 0;
  }
  __shared__ int sb[64], sh[64];
  sb[lane] = cb; sh[lane] = ch;
  __syncthreads();
  if (lane == 0) {
    int CB = 0, CH = 0;
    for (int t = 0; t < 64; ++t) { CB += sb[t]; CH += sh[t]; }
    int dt;
    if (CB >= 200) dt = 1;
    else if (CH >= 100) dt = 2;
    else dt = 0;
    hdr[slot] = dt;
  }
}

// ---------- KW: weights -> f32 blob ----------
extern "C" __global__ void __launch_bounds__(256)
kw_conv(const void* __restrict__ W1, const void* __restrict__ b1,
        const void* __restrict__ W2, const void* __restrict__ b2,
        const void* __restrict__ W3, const void* __restrict__ b3,
        const void* __restrict__ P1, const void* __restrict__ pb1,
        const void* __restrict__ P2, const void* __restrict__ pb2,
        const int* __restrict__ hdr, float* __restrict__ wf)
{
  int i = blockIdx.x * 256 + threadIdx.x;
  if (i >= W_TOTAL) return;
  const void* s; int o;
  if      (i < O_b1)  { s = W1;  o = i; }
  else if (i < O_W2)  { s = b1;  o = i - O_b1; }
  else if (i < O_b2)  { s = W2;  o = i - O_W2; }
  else if (i < O_W3)  { s = b2;  o = i - O_b2; }
  else if (i < O_b3)  { s = W3;  o = i - O_W3; }
  else if (i < O_P1)  { s = b3;  o = i - O_b3; }
  else if (i < O_pb1) { s = P1;  o = i - O_P1; }
  else if (i < O_P2)  { s = pb1; o = i - O_pb1; }
  else if (i < O_pb2) { s = P2;  o = i - O_P2; }
  else                { s = pb2; o = i - O_pb2; }
  wf[i] = ldf(s, o, hdr[1]);
}

// ---------- K2a: candidate flags (p0 > 0.5), no atomics ----------
extern "C" __global__ void __launch_bounds__(256)
k2a_cand(const void* __restrict__ opsv, const int* __restrict__ hdr,
         unsigned char* __restrict__ cand, int N)
{
  int i = blockIdx.x * 256 + threadIdx.x;
  if (i >= N) return;
  int dt = hdr[3];
  float x0 = ldf(opsv, (long)i * 4 + 0, dt);
  float x1 = ldf(opsv, (long)i * 4 + 1, dt);
  float x2 = ldf(opsv, (long)i * 4 + 2, dt);
  float x3 = ldf(opsv, (long)i * 4 + 3, dt);
  float m = fmaxf(fmaxf(x0, x1), fmaxf(x2, x3));
  double e0 = exp((double)(x0 - m));
  double e1 = exp((double)(x1 - m));
  double e2 = exp((double)(x2 - m));
  double e3 = exp((double)(x3 - m));
  double p0 = e0 / (((e0 + e1) + e2) + e3);
  cand[i] = (p0 > 0.5) ? 1 : 0;
}

// ---------- K1a: count degrees ONLY for candidate endpoints ----------
extern "C" __global__ void __launch_bounds__(256)
k1a_cnt(const int* __restrict__ ei, const unsigned char* __restrict__ cand,
        int* __restrict__ cnt, int E, const int* __restrict__ hdr)
{
  int e = blockIdx.x * 256 + threadIdx.x;
  if (e >= E) return;
  int is64 = hdr[2];
  int s = ldei(ei, e, is64);
  int d = ldei(ei, (long)E + e, is64);
  if (cand[s]) atomicAdd(cnt + s, 1);
  if (cand[d]) atomicAdd(cnt + d, 1);
}

// ---------- K2b: compact masked nodes + allocate adjacency regions ----------
extern "C" __global__ void __launch_bounds__(256)
k2b_alloc(const unsigned char* __restrict__ cand, const int* __restrict__ cnt,
          int* __restrict__ hdr, int* __restrict__ nodeoff,
          int* __restrict__ nlist, int N)
{
  int i = blockIdx.x * 256 + threadIdx.x;
  if (i >= N) return;
  int c = (cand[i] && cnt[i] > 0) ? cnt[i] : 0;
  if (c > 0) {
    int pos = atomicAdd(hdr + 4, 1);
    nlist[pos] = i;
    nodeoff[i] = atomicAdd(hdr + 5, c);
  } else {
    nodeoff[i] = -1;
  }
}

// ---------- K1b: fill adjacency lists of masked nodes ----------
extern "C" __global__ void __launch_bounds__(256)
k1_fill(const int* __restrict__ ei, const int* __restrict__ nodeoff,
        int* __restrict__ fillcnt, int* __restrict__ adj, int E,
        const int* __restrict__ hdr)
{
  int e = blockIdx.x * 256 + threadIdx.x;
  if (e >= E) return;
  int is64 = hdr[2];
  int s = ldei(ei, e, is64);
  int d = ldei(ei, (long)E + e, is64);
  int os = nodeoff[s];
  int od = nodeoff[d];
  if (os >= 0) { int p = atomicAdd(fillcnt + s, 1); adj[os + p] = d; }
  if (od >= 0) { int p = atomicAdd(fillcnt + d, 1); adj[od + p] = s; }
}

// ---------- K3a: neighbor mean, wave per masked node, persistent ----------
// writes mean into out[node*68 + 0..63] (masked rows are overwritten by k3b)
extern "C" __global__ void __launch_bounds__(256)
k3a_gather(const void* __restrict__ featv, const int* __restrict__ cnt,
           const int* __restrict__ nodeoff, const int* __restrict__ nlist,
           const int* __restrict__ adj, const int* __restrict__ hdr,
           float* __restrict__ out)
{
  const int lane = threadIdx.x & 63;
  const int q = __builtin_amdgcn_readfirstlane(threadIdx.x >> 6);
  const int dt = hdr[0];
  const int nmask = hdr[4];
  for (long b = (long)blockIdx.x * 4 + q; b < nmask; b += (long)gridDim.x * 4) {
    int node = nlist[b];
    int off = nodeoff[node];
    int dg = cnt[node];
    float acc = 0.f;
    int j = 0;
    for (; j + 4 <= dg; j += 4) {
      int n0 = adj[off + j + 0];
      int n1 = adj[off + j + 1];
      int n2 = adj[off + j + 2];
      int n3 = adj[off + j + 3];
      float v0 = ldf(featv, (long)n0 * 64 + lane, dt);
      float v1 = ldf(featv, (long)n1 * 64 + lane, dt);
      float v2 = ldf(featv, (long)n2 * 64 + lane, dt);
      float v3 = ldf(featv, (long)n3 * 64 + lane, dt);
      acc += ((v0 + v1) + (v2 + v3));
    }
    for (; j < dg; ++j)
      acc += ldf(featv, (long)adj[off + j] * 64 + lane, dt);
    out[(long)node * 68 + lane] = acc / (float)dg;
  }
}

// ---------- K3b: batched MLP, NPB=16 nodes/block ----------
// lane mapping per layer: node = tid&15, output-feature group = tid>>4.
// 16x more blocks than the 64-node version -> ~600+ working blocks at
// nmask~10k (vs ~150) so waves actually cover the 256 CUs.
// LDS: A,B are [128][LDW] f32 (17.4 KB total vs 66.5 KB before).
extern "C" __global__ void __launch_bounds__(256)
k3b_mlp(const void* __restrict__ featv, const int* __restrict__ nlist,
        const float* __restrict__ wf, const int* __restrict__ hdr,
        float* __restrict__ out)
{
  __shared__ float A[128 * LDW];
  __shared__ float B[128 * LDW];
  __shared__ int sNode[NPB];
  const int tid = threadIdx.x;
  const int nmask = hdr[4];
  const int base = blockIdx.x * NPB;
  if (nmask == 0 || base >= nmask) return;
  const int dt = hdr[0];

  if (tid < NPB) {
    int idx = base + tid;
    int cidx = (idx < nmask) ? idx : (nmask - 1);
    sNode[tid] = nlist[cidx];
  }
  __syncthreads();

  // stage ctx: A[f][nl], f<64 = node features, f=64..127 = neighbor mean (from k3a)
  // f fastest across threads -> coalesced global reads; LDS stride 17 -> conflict-free
#pragma unroll
  for (int i = 0; i < 8; ++i) {
    int g = i * 256 + tid;
    int f = g & 127;
    int nl = g >> 7;
    int node = sNode[nl];
    float v = (f < 64) ? ldf(featv, (long)node * 64 + f, dt)
                       : out[(long)node * 68 + (f - 64)];
    A[f * LDW + nl] = v;
  }
  __syncthreads();

  // L1: 128 -> 128, relu. thread: node nl=tid&15, 8 outputs j0..j0+7
  {
    const int nl = tid & 15;
    const int j0 = (tid >> 4) * 8;
    float a0 = wf[O_b1 + j0 + 0], a1 = wf[O_b1 + j0 + 1];
    float a2 = wf[O_b1 + j0 + 2], a3 = wf[O_b1 + j0 + 3];
    float a4 = wf[O_b1 + j0 + 4], a5 = wf[O_b1 + j0 + 5];
    float a6 = wf[O_b1 + j0 + 6], a7 = wf[O_b1 + j0 + 7];
#pragma unroll 4
    for (int k = 0; k < 128; ++k) {
      float x = A[k * LDW + nl];
      const float* w = wf + O_W1 + k * 128 + j0;
      float4 w0 = *(const float4*)(w);
      float4 w1 = *(const float4*)(w + 4);
      a0 = fmaf(x, w0.x, a0);
      a1 = fmaf(x, w0.y, a1);
      a2 = fmaf(x, w0.z, a2);
      a3 = fmaf(x, w0.w, a3);
      a4 = fmaf(x, w1.x, a4);
      a5 = fmaf(x, w1.y, a5);
      a6 = fmaf(x, w1.z, a6);
      a7 = fmaf(x, w1.w, a7);
    }
    B[(j0 + 0) * LDW + nl] = fmaxf(a0, 0.f);
    B[(j0 + 1) * LDW + nl] = fmaxf(a1, 0.f);
    B[(j0 + 2) * LDW + nl] = fmaxf(a2, 0.f);
    B[(j0 + 3) * LDW + nl] = fmaxf(a3, 0.f);
    B[(j0 + 4) * LDW + nl] = fmaxf(a4, 0.f);
    B[(j0 + 5) * LDW + nl] = fmaxf(a5, 0.f);
    B[(j0 + 6) * LDW + nl] = fmaxf(a6, 0.f);
    B[(j0 + 7) * LDW + nl] = fmaxf(a7, 0.f);
  }
  __syncthreads();

  // L2: 128 -> 64, relu. thread: 4 outputs j0..j0+3. writes A rows 0..63
  {
    const int nl = tid & 15;
    const int j0 = (tid >> 4) * 4;
    float a0 = wf[O_b2 + j0 + 0], a1 = wf[O_b2 + j0 + 1];
    float a2 = wf[O_b2 + j0 + 2], a3 = wf[O_b2 + j0 + 3];
#pragma unroll 4
    for (int k = 0; k < 128; ++k) {
      float x = B[k * LDW + nl];
      float4 w = *(const float4*)(wf + O_W2 + k * 64 + j0);
      a0 = fmaf(x, w.x, a0);
      a1 = fmaf(x, w.y, a1);
      a2 = fmaf(x, w.z, a2);
      a3 = fmaf(x, w.w, a3);
    }
    A[(j0 + 0) * LDW + nl] = fmaxf(a0, 0.f);
    A[(j0 + 1) * LDW + nl] = fmaxf(a1, 0.f);
    A[(j0 + 2) * LDW + nl] = fmaxf(a2, 0.f);
    A[(j0 + 3) * LDW + nl] = fmaxf(a3, 0.f);
  }
  __syncthreads();

  // L3: 64 -> 67 (no relu). thread: outputs jq, jq+16, jq+32, jq+48 (+64 if jq<3)
  {
    const int nl = tid & 15;
    const int jq = tid >> 4;            // 0..15
    const bool has5 = (jq < 3);
    float a0 = 0.f, a1 = 0.f, a2 = 0.f, a3 = 0.f, a4 = 0.f;
#pragma unroll 4
    for (int k = 0; k < 64; ++k) {
      float x = A[k * LDW + nl];
      const float* w = wf + O_W3 + k * 67 + jq;
      float w4 = has5 ? w[64] : 0.f;    // stays inside wf blob even at jq=15
      a0 = fmaf(x, w[0],  a0);
      a1 = fmaf(x, w[16], a1);
      a2 = fmaf(x, w[32], a2);
      a3 = fmaf(x, w[48], a3);
      a4 = fmaf(x, w4,    a4);
    }
    B[(jq +  0) * LDW + nl] = wf[O_b3 + jq]      + a0;
    B[(jq + 16) * LDW + nl] = wf[O_b3 + jq + 16] + a1;
    B[(jq + 32) * LDW + nl] = wf[O_b3 + jq + 32] + a2;
    B[(jq + 48) * LDW + nl] = wf[O_b3 + jq + 48] + a3;
    if (has5)
      B[(jq + 64) * LDW + nl] = wf[O_b3 + jq + 64] + a4;
  }
  __syncthreads();

  // L4: gen[3..66] -> 32, relu. thread: outputs jq, jq+16. writes A rows 0..31
  {
    const int nl = tid & 15;
    const int jq = tid >> 4;            // 0..15
    float a0 = wf[O_pb1 + jq], a1 = wf[O_pb1 + jq + 16];
#pragma unroll 4
    for (int k = 0; k < 64; ++k) {
      float x = B[(3 + k) * LDW + nl];
      a0 = fmaf(x, wf[O_P1 + k * 32 + jq],      a0);
      a1 = fmaf(x, wf[O_P1 + k * 32 + jq + 16], a1);
    }
    A[(jq +  0) * LDW + nl] = fmaxf(a0, 0.f);
    A[(jq + 16) * LDW + nl] = fmaxf(a1, 0.f);
  }
  __syncthreads();

  // L5: 32 -> sigmoid prob. wave 0: 4 partial lanes per node, shuffle-reduce
  if (tid < 64) {
    const int nl = tid & 15;
    const int part = tid >> 4;          // 0..3
    float p = 0.f;
#pragma unroll
    for (int kk = 0; kk < 8; ++kk) {
      int k = part * 8 + kk;
      p = fmaf(A[k * LDW + nl], wf[O_P2 + k], p);
    }
    p += __shfl_xor(p, 16);
    p += __shfl_xor(p, 32);
    if (part == 0) {
      float z = wf[O_pb2] + p;
      B[67 * LDW + nl] = 1.0f / (1.0f + expf(-z));
    }
  }
  __syncthreads();

  // store: 16 nodes x 68 channels, channel fastest -> coalesced 68-float runs
  for (int g = tid; g < NPB * 68; g += 256) {
    int nl = g / 68;
    int c = g - nl * 68;
    if (base + nl < nmask) {
      int node = sNode[nl];
      out[(long)node * 68 + c] = B[c * LDW + nl];
    }
  }
}

extern "C" void kernel_launch(void* const* d_in, const int* in_sizes, int n_in,
                              void* d_out, int out_size, void* d_ws, size_t ws_size,
                              hipStream_t stream) {
  // ---- identify tensors by element count (fallback: documented order) ----
  int iF = 0, iO = 1, iE = 2;
  int iW1 = 3, ib1 = 4, iW2 = 5, ib2 = 6, iW3 = 7, ib3 = 8;
  int iP1 = 9, ipb1 = 10, iP2 = 11, ipb2 = 12;
  {
    int bigs[4]; int nb = 0;
    for (int i = 0; i < n_in && nb < 4; ++i)
      if (in_sizes[i] > 100000) bigs[nb++] = i;
    if (nb == 3) {
      int a = bigs[0], b = bigs[1], c = bigs[2];
      int mx = a, mn = a;
      if (in_sizes[b] > in_sizes[mx]) mx = b;
      if (in_sizes[c] > in_sizes[mx]) mx = c;
      if (in_sizes[b] < in_sizes[mn]) mn = b;
      if (in_sizes[c] < in_sizes[mn]) mn = c;
      iF = mx; iO = mn; iE = a + b + c - mx - mn;
      int t32[2]; int n32 = 0;
      int jW1=-1, jb1=-1, jW2=-1, jb2=-1, jW3=-1, jb3=-1, jP1=-1, jpb2=-1;
      for (int i = 0; i < n_in; ++i) {
        if (i == iF || i == iO || i == iE) continue;
        switch (in_sizes[i]) {
          case 16384: jW1 = i; break;
          case 128:   jb1 = i; break;
          case 8192:  jW2 = i; break;
          case 64:    jb2 = i; break;
          case 4288:  jW3 = i; break;
          case 67:    jb3 = i; break;
          case 2048:  jP1 = i; break;
          case 1:     jpb2 = i; break;
          case 32:    if (n32 < 2) t32[n32++] = i; break;
          default: break;
        }
      }
      if (jW1 >= 0 && jb1 >= 0 && jW2 >= 0 && jb2 >= 0 && jW3 >= 0 &&
          jb3 >= 0 && jP1 >= 0 && jpb2 >= 0 && n32 == 2) {
        iW1 = jW1; ib1 = jb1; iW2 = jW2; ib2 = jb2; iW3 = jW3; ib3 = jb3;
        iP1 = jP1; ipb2 = jpb2;
        if (t32[1] == t32[0] + 1) { ipb1 = t32[0]; iP2 = t32[1]; }
        else                      { iP2 = t32[0]; ipb1 = t32[1]; }
      }
    }
  }
  int N = (out_size % 68 == 0) ? (out_size / 68) : (in_sizes[iF] / 64);
  const int E = in_sizes[iE] / 2;
  const void* feat = d_in[iF];
  const void* ops  = d_in[iO];
  const int* ei    = (const int*)d_in[iE];

  // workspace: hdr | wf | cand | cnt | nodeoff | fillcnt | nlist | adj(2E)
  char* ws = (char*)d_ws;
  int* hdr = (int*)ws;
  size_t off = 256;
  float* wf = (float*)(ws + off);
  off += ((size_t)W_TOTAL * 4 + 255) & ~(size_t)255;
  unsigned char* cand = (unsigned char*)(ws + off);
  off += ((size_t)N + 255) & ~(size_t)255;
  int* cnt = (int*)(ws + off);
  off += ((size_t)N * 4 + 255) & ~(size_t)255;
  int* nodeoff = (int*)(ws + off);
  off += ((size_t)N * 4 + 255) & ~(size_t)255;
  int* fillcnt = (int*)(ws + off);
  off += ((size_t)N * 4 + 255) & ~(size_t)255;
  int* nlist = (int*)(ws + off);
  off += ((size_t)N * 4 + 255) & ~(size_t)255;
  int* adj = (int*)(ws + off);

  hipMemsetAsync(hdr, 0, 256, stream);
  hipMemsetAsync(cnt, 0, (size_t)N * 4, stream);
  hipMemsetAsync(fillcnt, 0, (size_t)N * 4, stream);
  hipMemsetAsync(d_out, 0, (size_t)out_size * 4, stream);

  kall_detect<<<4, 64, 0, stream>>>((const u32*)feat, (const u32*)d_in[iW1],
                                    (const u32*)ops, (const u32*)ei, hdr);

  kw_conv<<<(W_TOTAL + 255) / 256, 256, 0, stream>>>(
      d_in[iW1], d_in[ib1], d_in[iW2], d_in[ib2], d_in[iW3], d_in[ib3],
      d_in[iP1], d_in[ipb1], d_in[iP2], d_in[ipb2], hdr, wf);
  k2a_cand<<<(N + 255) / 256, 256, 0, stream>>>(ops, hdr, cand, N);
  k1a_cnt<<<(E + 255) / 256, 256, 0, stream>>>(ei, cand, cnt, E, hdr);
  k2b_alloc<<<(N + 255) / 256, 256, 0, stream>>>(cand, cnt, hdr, nodeoff, nlist, N);
  k1_fill<<<(E + 255) / 256, 256, 0, stream>>>(ei, nodeoff, fillcnt, adj, E, hdr);
  k3a_gather<<<2048, 256, 0, stream>>>(feat, cnt, nodeoff, nlist, adj, hdr,
                                       (float*)d_out);
  k3b_mlp<<<(N + NPB - 1) / NPB, 256, 0, stream>>>(feat, nlist, wf, hdr,
                                                   (float*)d_out);
}

// Round 4
// 264.166 us; speedup vs baseline: 1.1198x; 1.0270x over previous
//
#include <hip/hip_runtime.h>
#include <hip/hip_bf16.h>
#include <hip/hip_fp16.h>
#include <math.h>

typedef unsigned int u32;
typedef unsigned short u16;
typedef unsigned long long u64;

// f32 weight-blob offsets (in floats)
#define O_W1 0
#define O_b1 16384
#define O_W2 16512
#define O_b2 24704
#define O_W3 24768
#define O_b3 29056
#define O_P1 29123
#define O_pb1 31171
#define O_P2 31203
#define O_pb2 31235
#define W_TOTAL 31236

#define NPB 16   // nodes per block in k3b
#define LDW 17   // node-dim pad (17 odd -> conflict-free strided LDS)

// dt codes: 0 = f32, 1 = bf16, 2 = f16
__device__ __forceinline__ float ldf(const void* p, long i, int dt) {
  if (dt == 1) { u32 v = ((const u16*)p)[i]; return __uint_as_float(v << 16); }
  if (dt == 2) { __half h = ((const __half*)p)[i]; return __half2float(h); }
  return ((const float*)p)[i];
}
__device__ __forceinline__ int ldei(const int* p, long i, int is64) {
  return is64 ? p[2 * i] : p[i];
}
__device__ __forceinline__ int bit_test(const u64* bits, int i) {
  return (int)((bits[i >> 6] >> (i & 63)) & 1ull);
}

// hdr: [0]=dt_feat [1]=dt_w [2]=ei is64 [3]=dt_ops [4]=masked count [5]=adj total
// ---------- merged detectors: block 0=feat,1=W1,2=ops,3=ei ----------
extern "C" __global__ void kall_detect(const u32* __restrict__ feat,
                                       const u32* __restrict__ w1,
                                       const u32* __restrict__ ops,
                                       const u32* __restrict__ ei,
                                       int* __restrict__ hdr)
{
  int lane = threadIdx.x;                 // 64 threads/block
  int mode = blockIdx.x;
  if (mode == 3) {                        // int64 edge check
    unsigned long long m0 = __ballot(ei[lane] == 0u);
    unsigned long long m1 = __ballot(ei[64 + lane] == 0u);
    if (lane == 0) hdr[2] = (__popcll(m0) + __popcll(m1) >= 32) ? 1 : 0;
    return;
  }
  const u32* p = (mode == 0) ? feat : (mode == 1) ? w1 : ops;
  int slot = (mode == 0) ? 0 : (mode == 1) ? 1 : 3;
  u32 w0 = p[lane];
  u32 w1v = p[64 + lane];
  u16 h[4] = { (u16)(w0 & 0xffff), (u16)(w0 >> 16),
               (u16)(w1v & 0xffff), (u16)(w1v >> 16) };
  int cb = 0;
#pragma unroll
  for (int t = 0; t < 4; ++t) {
    int e8 = (h[t] >> 7) & 0xff;
    cb += (e8 >= 110 && e8 <= 140) ? 1 : 0;
  }
  int ch = 0;                              // f16 check on EVEN u16s only
#pragma unroll
  for (int t = 0; t < 4; t += 2) {
    int e5 = (h[t] >> 10) & 0x1f;
    ch += (e5 >= 5 && e5 <= 18) ? 1 : 0;
  }
  __shared__ int sb[64], sh[64];
  sb[lane] = cb; sh[lane] = ch;
  __syncthreads();
  if (lane == 0) {
    int CB = 0, CH = 0;
    for (int t = 0; t < 64; ++t) { CB += sb[t]; CH += sh[t]; }
    int dt;
    if (CB >= 200) dt = 1;
    else if (CH >= 100) dt = 2;
    else dt = 0;
    hdr[slot] = dt;
  }
}

// ---------- KW: weights -> f32 blob ----------
extern "C" __global__ void __launch_bounds__(256)
kw_conv(const void* __restrict__ W1, const void* __restrict__ b1,
        const void* __restrict__ W2, const void* __restrict__ b2,
        const void* __restrict__ W3, const void* __restrict__ b3,
        const void* __restrict__ P1, const void* __restrict__ pb1,
        const void* __restrict__ P2, const void* __restrict__ pb2,
        const int* __restrict__ hdr, float* __restrict__ wf)
{
  int i = blockIdx.x * 256 + threadIdx.x;
  if (i >= W_TOTAL) return;
  const void* s; int o;
  if      (i < O_b1)  { s = W1;  o = i; }
  else if (i < O_W2)  { s = b1;  o = i - O_b1; }
  else if (i < O_b2)  { s = W2;  o = i - O_W2; }
  else if (i < O_W3)  { s = b2;  o = i - O_b2; }
  else if (i < O_b3)  { s = W3;  o = i - O_W3; }
  else if (i < O_P1)  { s = b3;  o = i - O_b3; }
  else if (i < O_pb1) { s = P1;  o = i - O_P1; }
  else if (i < O_P2)  { s = pb1; o = i - O_pb1; }
  else if (i < O_pb2) { s = P2;  o = i - O_P2; }
  else                { s = pb2; o = i - O_pb2; }
  wf[i] = ldf(s, o, hdr[1]);
}

// ---------- K2a: candidate bitmask (p0 > 0.5) via wave ballot ----------
extern "C" __global__ void __launch_bounds__(256)
k2a_cand(const void* __restrict__ opsv, const int* __restrict__ hdr,
         u64* __restrict__ bits, int N)
{
  int i = blockIdx.x * 256 + threadIdx.x;
  if (i >= N) return;
  int dt = hdr[3];
  float x0 = ldf(opsv, (long)i * 4 + 0, dt);
  float x1 = ldf(opsv, (long)i * 4 + 1, dt);
  float x2 = ldf(opsv, (long)i * 4 + 2, dt);
  float x3 = ldf(opsv, (long)i * 4 + 3, dt);
  float m = fmaxf(fmaxf(x0, x1), fmaxf(x2, x3));
  double e0 = exp((double)(x0 - m));
  double e1 = exp((double)(x1 - m));
  double e2 = exp((double)(x2 - m));
  double e3 = exp((double)(x3 - m));
  double p0 = e0 / (((e0 + e1) + e2) + e3);
  u64 msk = __ballot(p0 > 0.5);
  if ((threadIdx.x & 63) == 0) bits[i >> 6] = msk;
}

// ---------- K1a: count degrees ONLY for candidate endpoints ----------
extern "C" __global__ void __launch_bounds__(256)
k1a_cnt(const int* __restrict__ ei, const u64* __restrict__ bits,
        int* __restrict__ cnt, int E, const int* __restrict__ hdr)
{
  int e = blockIdx.x * 256 + threadIdx.x;
  if (e >= E) return;
  int is64 = hdr[2];
  int s = ldei(ei, e, is64);
  int d = ldei(ei, (long)E + e, is64);
  if (bit_test(bits, s)) atomicAdd(cnt + s, 1);
  if (bit_test(bits, d)) atomicAdd(cnt + d, 1);
}

// ---------- K2b: compact masked nodes + allocate adjacency regions ----------
extern "C" __global__ void __launch_bounds__(256)
k2b_alloc(const u64* __restrict__ bits, const int* __restrict__ cnt,
          int* __restrict__ hdr, int* __restrict__ nodeoff,
          int* __restrict__ nlist, int N)
{
  int i = blockIdx.x * 256 + threadIdx.x;
  if (i >= N) return;
  int c = (bit_test(bits, i) && cnt[i] > 0) ? cnt[i] : 0;
  if (c > 0) {
    int pos = atomicAdd(hdr + 4, 1);
    nlist[pos] = i;
    nodeoff[i] = atomicAdd(hdr + 5, c);
  } else {
    nodeoff[i] = -1;
  }
}

// ---------- K1b: fill adjacency lists of masked nodes ----------
extern "C" __global__ void __launch_bounds__(256)
k1_fill(const int* __restrict__ ei, const u64* __restrict__ bits,
        const int* __restrict__ nodeoff,
        int* __restrict__ fillcnt, int* __restrict__ adj, int E,
        const int* __restrict__ hdr)
{
  int e = blockIdx.x * 256 + threadIdx.x;
  if (e >= E) return;
  int is64 = hdr[2];
  int s = ldei(ei, e, is64);
  int d = ldei(ei, (long)E + e, is64);
  if (bit_test(bits, s)) {
    int os = nodeoff[s];
    if (os >= 0) { int p = atomicAdd(fillcnt + s, 1); adj[os + p] = d; }
  }
  if (bit_test(bits, d)) {
    int od = nodeoff[d];
    if (od >= 0) { int p = atomicAdd(fillcnt + d, 1); adj[od + p] = s; }
  }
}

// ---------- K3a: neighbor mean, wave per masked node, persistent ----------
// f32 fast path: lane = (neighbor slot g 0..3, float4 col fq 0..15);
// 4 rows fetched per wave-instr at 16 B/lane, shuffle-reduce across slots.
extern "C" __global__ void __launch_bounds__(256)
k3a_gather(const void* __restrict__ featv, const int* __restrict__ cnt,
           const int* __restrict__ nodeoff, const int* __restrict__ nlist,
           const int* __restrict__ adj, const int* __restrict__ hdr,
           float* __restrict__ out)
{
  const int lane = threadIdx.x & 63;
  const int q = __builtin_amdgcn_readfirstlane(threadIdx.x >> 6);
  const int dt = hdr[0];
  const int nmask = hdr[4];
  if (dt == 0) {
    const float4* f4 = (const float4*)featv;
    const int g = lane >> 4;       // neighbor slot
    const int fq = lane & 15;      // float4 column in row
    for (long b = (long)blockIdx.x * 4 + q; b < nmask; b += (long)gridDim.x * 4) {
      int node = nlist[b];
      int off = nodeoff[node];
      int dg = cnt[node];
      float4 acc = make_float4(0.f, 0.f, 0.f, 0.f);
      int j = g;
      for (; j + 4 < dg; j += 8) {
        int n0 = adj[off + j];
        int n1 = adj[off + j + 4];
        float4 v0 = f4[(long)n0 * 16 + fq];
        float4 v1 = f4[(long)n1 * 16 + fq];
        acc.x += v0.x + v1.x; acc.y += v0.y + v1.y;
        acc.z += v0.z + v1.z; acc.w += v0.w + v1.w;
      }
      if (j < dg) {
        int n0 = adj[off + j];
        float4 v0 = f4[(long)n0 * 16 + fq];
        acc.x += v0.x; acc.y += v0.y; acc.z += v0.z; acc.w += v0.w;
      }
      acc.x += __shfl_xor(acc.x, 16); acc.y += __shfl_xor(acc.y, 16);
      acc.z += __shfl_xor(acc.z, 16); acc.w += __shfl_xor(acc.w, 16);
      acc.x += __shfl_xor(acc.x, 32); acc.y += __shfl_xor(acc.y, 32);
      acc.z += __shfl_xor(acc.z, 32); acc.w += __shfl_xor(acc.w, 32);
      if (g == 0) {
        float inv = 1.f / (float)dg;
        float4 r = make_float4(acc.x * inv, acc.y * inv, acc.z * inv, acc.w * inv);
        *(float4*)(out + (long)node * 68 + fq * 4) = r;
      }
    }
  } else {
    // generic scalar path (bf16/f16 features)
    for (long b = (long)blockIdx.x * 4 + q; b < nmask; b += (long)gridDim.x * 4) {
      int node = nlist[b];
      int off = nodeoff[node];
      int dg = cnt[node];
      float acc = 0.f;
      int j = 0;
      for (; j + 4 <= dg; j += 4) {
        int n0 = adj[off + j + 0];
        int n1 = adj[off + j + 1];
        int n2 = adj[off + j + 2];
        int n3 = adj[off + j + 3];
        float v0 = ldf(featv, (long)n0 * 64 + lane, dt);
        float v1 = ldf(featv, (long)n1 * 64 + lane, dt);
        float v2 = ldf(featv, (long)n2 * 64 + lane, dt);
        float v3 = ldf(featv, (long)n3 * 64 + lane, dt);
        acc += ((v0 + v1) + (v2 + v3));
      }
      for (; j < dg; ++j)
        acc += ldf(featv, (long)adj[off + j] * 64 + lane, dt);
      out[(long)node * 68 + lane] = acc / (float)dg;
    }
  }
}

// ---------- K3b: batched MLP, NPB=16 nodes/block (round-1 measured-good) ----------
// lane mapping per layer: node = tid&15, output-feature group = tid>>4.
extern "C" __global__ void __launch_bounds__(256)
k3b_mlp(const void* __restrict__ featv, const int* __restrict__ nlist,
        const float* __restrict__ wf, const int* __restrict__ hdr,
        float* __restrict__ out)
{
  __shared__ float A[128 * LDW];
  __shared__ float B[128 * LDW];
  __shared__ int sNode[NPB];
  const int tid = threadIdx.x;
  const int nmask = hdr[4];
  const int base = blockIdx.x * NPB;
  if (nmask == 0 || base >= nmask) return;
  const int dt = hdr[0];

  if (tid < NPB) {
    int idx = base + tid;
    int cidx = (idx < nmask) ? idx : (nmask - 1);
    sNode[tid] = nlist[cidx];
  }
  __syncthreads();

  // stage ctx: A[f][nl], f<64 = node features, f=64..127 = neighbor mean (from k3a)
#pragma unroll
  for (int i = 0; i < 8; ++i) {
    int g = i * 256 + tid;
    int f = g & 127;
    int nl = g >> 7;
    int node = sNode[nl];
    float v = (f < 64) ? ldf(featv, (long)node * 64 + f, dt)
                       : out[(long)node * 68 + (f - 64)];
    A[f * LDW + nl] = v;
  }
  __syncthreads();

  // L1: 128 -> 128, relu. thread: node nl=tid&15, 8 outputs j0..j0+7
  {
    const int nl = tid & 15;
    const int j0 = (tid >> 4) * 8;
    float a0 = wf[O_b1 + j0 + 0], a1 = wf[O_b1 + j0 + 1];
    float a2 = wf[O_b1 + j0 + 2], a3 = wf[O_b1 + j0 + 3];
    float a4 = wf[O_b1 + j0 + 4], a5 = wf[O_b1 + j0 + 5];
    float a6 = wf[O_b1 + j0 + 6], a7 = wf[O_b1 + j0 + 7];
#pragma unroll 4
    for (int k = 0; k < 128; ++k) {
      float x = A[k * LDW + nl];
      const float* w = wf + O_W1 + k * 128 + j0;
      float4 w0 = *(const float4*)(w);
      float4 w1 = *(const float4*)(w + 4);
      a0 = fmaf(x, w0.x, a0);
      a1 = fmaf(x, w0.y, a1);
      a2 = fmaf(x, w0.z, a2);
      a3 = fmaf(x, w0.w, a3);
      a4 = fmaf(x, w1.x, a4);
      a5 = fmaf(x, w1.y, a5);
      a6 = fmaf(x, w1.z, a6);
      a7 = fmaf(x, w1.w, a7);
    }
    B[(j0 + 0) * LDW + nl] = fmaxf(a0, 0.f);
    B[(j0 + 1) * LDW + nl] = fmaxf(a1, 0.f);
    B[(j0 + 2) * LDW + nl] = fmaxf(a2, 0.f);
    B[(j0 + 3) * LDW + nl] = fmaxf(a3, 0.f);
    B[(j0 + 4) * LDW + nl] = fmaxf(a4, 0.f);
    B[(j0 + 5) * LDW + nl] = fmaxf(a5, 0.f);
    B[(j0 + 6) * LDW + nl] = fmaxf(a6, 0.f);
    B[(j0 + 7) * LDW + nl] = fmaxf(a7, 0.f);
  }
  __syncthreads();

  // L2: 128 -> 64, relu. thread: 4 outputs j0..j0+3. writes A rows 0..63
  {
    const int nl = tid & 15;
    const int j0 = (tid >> 4) * 4;
    float a0 = wf[O_b2 + j0 + 0], a1 = wf[O_b2 + j0 + 1];
    float a2 = wf[O_b2 + j0 + 2], a3 = wf[O_b2 + j0 + 3];
#pragma unroll 4
    for (int k = 0; k < 128; ++k) {
      float x = B[k * LDW + nl];
      float4 w = *(const float4*)(wf + O_W2 + k * 64 + j0);
      a0 = fmaf(x, w.x, a0);
      a1 = fmaf(x, w.y, a1);
      a2 = fmaf(x, w.z, a2);
      a3 = fmaf(x, w.w, a3);
    }
    A[(j0 + 0) * LDW + nl] = fmaxf(a0, 0.f);
    A[(j0 + 1) * LDW + nl] = fmaxf(a1, 0.f);
    A[(j0 + 2) * LDW + nl] = fmaxf(a2, 0.f);
    A[(j0 + 3) * LDW + nl] = fmaxf(a3, 0.f);
  }
  __syncthreads();

  // L3: 64 -> 67 (no relu). thread: outputs jq, jq+16, jq+32, jq+48 (+64 if jq<3)
  {
    const int nl = tid & 15;
    const int jq = tid >> 4;            // 0..15
    const bool has5 = (jq < 3);
    float a0 = 0.f, a1 = 0.f, a2 = 0.f, a3 = 0.f, a4 = 0.f;
#pragma unroll 4
    for (int k = 0; k < 64; ++k) {
      float x = A[k * LDW + nl];
      const float* w = wf + O_W3 + k * 67 + jq;
      float w4 = has5 ? w[64] : 0.f;    // stays inside wf blob even at jq=15
      a0 = fmaf(x, w[0],  a0);
      a1 = fmaf(x, w[16], a1);
      a2 = fmaf(x, w[32], a2);
      a3 = fmaf(x, w[48], a3);
      a4 = fmaf(x, w4,    a4);
    }
    B[(jq +  0) * LDW + nl] = wf[O_b3 + jq]      + a0;
    B[(jq + 16) * LDW + nl] = wf[O_b3 + jq + 16] + a1;
    B[(jq + 32) * LDW + nl] = wf[O_b3 + jq + 32] + a2;
    B[(jq + 48) * LDW + nl] = wf[O_b3 + jq + 48] + a3;
    if (has5)
      B[(jq + 64) * LDW + nl] = wf[O_b3 + jq + 64] + a4;
  }
  __syncthreads();

  // L4: gen[3..66] -> 32, relu. thread: outputs jq, jq+16. writes A rows 0..31
  {
    const int nl = tid & 15;
    const int jq = tid >> 4;            // 0..15
    float a0 = wf[O_pb1 + jq], a1 = wf[O_pb1 + jq + 16];
#pragma unroll 4
    for (int k = 0; k < 64; ++k) {
      float x = B[(3 + k) * LDW + nl];
      a0 = fmaf(x, wf[O_P1 + k * 32 + jq],      a0);
      a1 = fmaf(x, wf[O_P1 + k * 32 + jq + 16], a1);
    }
    A[(jq +  0) * LDW + nl] = fmaxf(a0, 0.f);
    A[(jq + 16) * LDW + nl] = fmaxf(a1, 0.f);
  }
  __syncthreads();

  // L5: 32 -> sigmoid prob. wave 0: 4 partial lanes per node, shuffle-reduce
  if (tid < 64) {
    const int nl = tid & 15;
    const int part = tid >> 4;          // 0..3
    float p = 0.f;
#pragma unroll
    for (int kk = 0; kk < 8; ++kk) {
      int k = part * 8 + kk;
      p = fmaf(A[k * LDW + nl], wf[O_P2 + k], p);
    }
    p += __shfl_xor(p, 16);
    p += __shfl_xor(p, 32);
    if (part == 0) {
      float z = wf[O_pb2] + p;
      B[67 * LDW + nl] = 1.0f / (1.0f + expf(-z));
    }
  }
  __syncthreads();

  // store: 16 nodes x 68 channels, channel fastest -> coalesced 68-float runs
  for (int g = tid; g < NPB * 68; g += 256) {
    int nl = g / 68;
    int c = g - nl * 68;
    if (base + nl < nmask) {
      int node = sNode[nl];
      out[(long)node * 68 + c] = B[c * LDW + nl];
    }
  }
}

extern "C" void kernel_launch(void* const* d_in, const int* in_sizes, int n_in,
                              void* d_out, int out_size, void* d_ws, size_t ws_size,
                              hipStream_t stream) {
  // ---- identify tensors by element count (fallback: documented order) ----
  int iF = 0, iO = 1, iE = 2;
  int iW1 = 3, ib1 = 4, iW2 = 5, ib2 = 6, iW3 = 7, ib3 = 8;
  int iP1 = 9, ipb1 = 10, iP2 = 11, ipb2 = 12;
  {
    int bigs[4]; int nb = 0;
    for (int i = 0; i < n_in && nb < 4; ++i)
      if (in_sizes[i] > 100000) bigs[nb++] = i;
    if (nb == 3) {
      int a = bigs[0], b = bigs[1], c = bigs[2];
      int mx = a, mn = a;
      if (in_sizes[b] > in_sizes[mx]) mx = b;
      if (in_sizes[c] > in_sizes[mx]) mx = c;
      if (in_sizes[b] < in_sizes[mn]) mn = b;
      if (in_sizes[c] < in_sizes[mn]) mn = c;
      iF = mx; iO = mn; iE = a + b + c - mx - mn;
      int t32[2]; int n32 = 0;
      int jW1=-1, jb1=-1, jW2=-1, jb2=-1, jW3=-1, jb3=-1, jP1=-1, jpb2=-1;
      for (int i = 0; i < n_in; ++i) {
        if (i == iF || i == iO || i == iE) continue;
        switch (in_sizes[i]) {
          case 16384: jW1 = i; break;
          case 128:   jb1 = i; break;
          case 8192:  jW2 = i; break;
          case 64:    jb2 = i; break;
          case 4288:  jW3 = i; break;
          case 67:    jb3 = i; break;
          case 2048:  jP1 = i; break;
          case 1:     jpb2 = i; break;
          case 32:    if (n32 < 2) t32[n32++] = i; break;
          default: break;
        }
      }
      if (jW1 >= 0 && jb1 >= 0 && jW2 >= 0 && jb2 >= 0 && jW3 >= 0 &&
          jb3 >= 0 && jP1 >= 0 && jpb2 >= 0 && n32 == 2) {
        iW1 = jW1; ib1 = jb1; iW2 = jW2; ib2 = jb2; iW3 = jW3; ib3 = jb3;
        iP1 = jP1; ipb2 = jpb2;
        if (t32[1] == t32[0] + 1) { ipb1 = t32[0]; iP2 = t32[1]; }
        else                      { iP2 = t32[0]; ipb1 = t32[1]; }
      }
    }
  }
  int N = (out_size % 68 == 0) ? (out_size / 68) : (in_sizes[iF] / 64);
  const int E = in_sizes[iE] / 2;
  const void* feat = d_in[iF];
  const void* ops  = d_in[iO];
  const int* ei    = (const int*)d_in[iE];

  // workspace: hdr | wf | bits | cnt | nodeoff | fillcnt | nlist | adj(2E)
  char* ws = (char*)d_ws;
  int* hdr = (int*)ws;
  size_t off = 256;
  float* wf = (float*)(ws + off);
  off += ((size_t)W_TOTAL * 4 + 255) & ~(size_t)255;
  u64* bits = (u64*)(ws + off);
  off += (((size_t)(N + 63) / 64) * 8 + 255) & ~(size_t)255;
  int* cnt = (int*)(ws + off);
  off += ((size_t)N * 4 + 255) & ~(size_t)255;
  int* nodeoff = (int*)(ws + off);
  off += ((size_t)N * 4 + 255) & ~(size_t)255;
  int* fillcnt = (int*)(ws + off);
  off += ((size_t)N * 4 + 255) & ~(size_t)255;
  int* nlist = (int*)(ws + off);
  off += ((size_t)N * 4 + 255) & ~(size_t)255;
  int* adj = (int*)(ws + off);

  hipMemsetAsync(hdr, 0, 256, stream);
  hipMemsetAsync(cnt, 0, (size_t)N * 4, stream);
  hipMemsetAsync(fillcnt, 0, (size_t)N * 4, stream);
  hipMemsetAsync(d_out, 0, (size_t)out_size * 4, stream);

  kall_detect<<<4, 64, 0, stream>>>((const u32*)feat, (const u32*)d_in[iW1],
                                    (const u32*)ops, (const u32*)ei, hdr);

  kw_conv<<<(W_TOTAL + 255) / 256, 256, 0, stream>>>(
      d_in[iW1], d_in[ib1], d_in[iW2], d_in[ib2], d_in[iW3], d_in[ib3],
      d_in[iP1], d_in[ipb1], d_in[iP2], d_in[ipb2], hdr, wf);
  k2a_cand<<<(N + 255) / 256, 256, 0, stream>>>(ops, hdr, bits, N);
  k1a_cnt<<<(E + 255) / 256, 256, 0, stream>>>(ei, bits, cnt, E, hdr);
  k2b_alloc<<<(N + 255) / 256, 256, 0, stream>>>(bits, cnt, hdr, nodeoff, nlist, N);
  k1_fill<<<(E + 255) / 256, 256, 0, stream>>>(ei, bits, nodeoff, fillcnt, adj, E, hdr);
  k3a_gather<<<2048, 256, 0, stream>>>(feat, cnt, nodeoff, nlist, adj, hdr,
                                       (float*)d_out);
  k3b_mlp<<<(N + NPB - 1) / NPB, 256, 0, stream>>>(feat, nlist, wf, hdr,
                                                   (float*)d_out);
}

// Round 5
// 240.454 us; speedup vs baseline: 1.2302x; 1.0986x over previous
//
#include <hip/hip_runtime.h>
#include <hip/hip_bf16.h>
#include <hip/hip_fp16.h>
#include <math.h>

typedef unsigned int u32;
typedef unsigned short u16;
typedef unsigned long long u64;

// f32 weight-blob offsets (in floats)
#define O_W1 0
#define O_b1 16384
#define O_W2 16512
#define O_b2 24704
#define O_W3 24768
#define O_b3 29056
#define O_P1 29123
#define O_pb1 31171
#define O_P2 31203
#define O_pb2 31235
#define W_TOTAL 31236

#define NPB 16   // nodes per block in k3b
#define LDW 17   // node-dim pad (17 odd -> conflict-free strided LDS)

// dt codes: 0 = f32, 1 = bf16, 2 = f16
__device__ __forceinline__ float ldf(const void* p, long i, int dt) {
  if (dt == 1) { u32 v = ((const u16*)p)[i]; return __uint_as_float(v << 16); }
  if (dt == 2) { __half h = ((const __half*)p)[i]; return __half2float(h); }
  return ((const float*)p)[i];
}
__device__ __forceinline__ int ldei(const int* p, long i, int is64) {
  return is64 ? p[2 * i] : p[i];
}
__device__ __forceinline__ int bit_test(const u64* bits, int i) {
  return (int)((bits[i >> 6] >> (i & 63)) & 1ull);
}

// hdr: [0]=dt_feat [1]=dt_w [2]=ei is64 [3]=dt_ops [4]=masked count [5]=adj total
// ---------- merged detectors: block 0=feat,1=W1,2=ops,3=ei ----------
extern "C" __global__ void kall_detect(const u32* __restrict__ feat,
                                       const u32* __restrict__ w1,
                                       const u32* __restrict__ ops,
                                       const u32* __restrict__ ei,
                                       int* __restrict__ hdr)
{
  int lane = threadIdx.x;                 // 64 threads/block
  int mode = blockIdx.x;
  if (mode == 3) {                        // int64 edge check
    unsigned long long m0 = __ballot(ei[lane] == 0u);
    unsigned long long m1 = __ballot(ei[64 + lane] == 0u);
    if (lane == 0) hdr[2] = (__popcll(m0) + __popcll(m1) >= 32) ? 1 : 0;
    return;
  }
  const u32* p = (mode == 0) ? feat : (mode == 1) ? w1 : ops;
  int slot = (mode == 0) ? 0 : (mode == 1) ? 1 : 3;
  u32 w0 = p[lane];
  u32 w1v = p[64 + lane];
  u16 h[4] = { (u16)(w0 & 0xffff), (u16)(w0 >> 16),
               (u16)(w1v & 0xffff), (u16)(w1v >> 16) };
  int cb = 0;
#pragma unroll
  for (int t = 0; t < 4; ++t) {
    int e8 = (h[t] >> 7) & 0xff;
    cb += (e8 >= 110 && e8 <= 140) ? 1 : 0;
  }
  int ch = 0;                              // f16 check on EVEN u16s only
#pragma unroll
  for (int t = 0; t < 4; t += 2) {
    int e5 = (h[t] >> 10) & 0x1f;
    ch += (e5 >= 5 && e5 <= 18) ? 1 : 0;
  }
  __shared__ int sb[64], sh[64];
  sb[lane] = cb; sh[lane] = ch;
  __syncthreads();
  if (lane == 0) {
    int CB = 0, CH = 0;
    for (int t = 0; t < 64; ++t) { CB += sb[t]; CH += sh[t]; }
    int dt;
    if (CB >= 200) dt = 1;
    else if (CH >= 100) dt = 2;
    else dt = 0;
    hdr[slot] = dt;
  }
}

// ---------- KW: weights -> f32 blob ----------
extern "C" __global__ void __launch_bounds__(256)
kw_conv(const void* __restrict__ W1, const void* __restrict__ b1,
        const void* __restrict__ W2, const void* __restrict__ b2,
        const void* __restrict__ W3, const void* __restrict__ b3,
        const void* __restrict__ P1, const void* __restrict__ pb1,
        const void* __restrict__ P2, const void* __restrict__ pb2,
        const int* __restrict__ hdr, float* __restrict__ wf)
{
  int i = blockIdx.x * 256 + threadIdx.x;
  if (i >= W_TOTAL) return;
  const void* s; int o;
  if      (i < O_b1)  { s = W1;  o = i; }
  else if (i < O_W2)  { s = b1;  o = i - O_b1; }
  else if (i < O_b2)  { s = W2;  o = i - O_W2; }
  else if (i < O_W3)  { s = b2;  o = i - O_b2; }
  else if (i < O_b3)  { s = W3;  o = i - O_W3; }
  else if (i < O_P1)  { s = b3;  o = i - O_b3; }
  else if (i < O_pb1) { s = P1;  o = i - O_P1; }
  else if (i < O_P2)  { s = pb1; o = i - O_pb1; }
  else if (i < O_pb2) { s = P2;  o = i - O_P2; }
  else                { s = pb2; o = i - O_pb2; }
  wf[i] = ldf(s, o, hdr[1]);
}

// ---------- K2a: candidate bitmask (p0 > 0.5) via ballot; also zeroes cnt/fillcnt ----------
extern "C" __global__ void __launch_bounds__(256)
k2a_cand(const void* __restrict__ opsv, const int* __restrict__ hdr,
         u64* __restrict__ bits, int* __restrict__ cnt,
         int* __restrict__ fillcnt, int N)
{
  int i = blockIdx.x * 256 + threadIdx.x;
  if (i >= N) return;
  cnt[i] = 0;
  fillcnt[i] = 0;
  int dt = hdr[3];
  float x0 = ldf(opsv, (long)i * 4 + 0, dt);
  float x1 = ldf(opsv, (long)i * 4 + 1, dt);
  float x2 = ldf(opsv, (long)i * 4 + 2, dt);
  float x3 = ldf(opsv, (long)i * 4 + 3, dt);
  float m = fmaxf(fmaxf(x0, x1), fmaxf(x2, x3));
  double e0 = exp((double)(x0 - m));
  double e1 = exp((double)(x1 - m));
  double e2 = exp((double)(x2 - m));
  double e3 = exp((double)(x3 - m));
  double p0 = e0 / (((e0 + e1) + e2) + e3);
  u64 msk = __ballot(p0 > 0.5);
  if ((threadIdx.x & 63) == 0) bits[i >> 6] = msk;
}

// ---------- K1a: count degrees ONLY for candidate endpoints ----------
extern "C" __global__ void __launch_bounds__(256)
k1a_cnt(const int* __restrict__ ei, const u64* __restrict__ bits,
        int* __restrict__ cnt, int E, const int* __restrict__ hdr)
{
  int e = blockIdx.x * 256 + threadIdx.x;
  if (e >= E) return;
  int is64 = hdr[2];
  int s = ldei(ei, e, is64);
  int d = ldei(ei, (long)E + e, is64);
  if (bit_test(bits, s)) atomicAdd(cnt + s, 1);
  if (bit_test(bits, d)) atomicAdd(cnt + d, 1);
}

// ---------- K2b: compact masked nodes + allocate adjacency regions ----------
extern "C" __global__ void __launch_bounds__(256)
k2b_alloc(const u64* __restrict__ bits, const int* __restrict__ cnt,
          int* __restrict__ hdr, int* __restrict__ nodeoff,
          int* __restrict__ nlist, int N)
{
  int i = blockIdx.x * 256 + threadIdx.x;
  if (i >= N) return;
  int c = (bit_test(bits, i) && cnt[i] > 0) ? cnt[i] : 0;
  if (c > 0) {
    int pos = atomicAdd(hdr + 4, 1);
    nlist[pos] = i;
    nodeoff[i] = atomicAdd(hdr + 5, c);
  } else {
    nodeoff[i] = -1;
  }
}

// ---------- K1b: fill adjacency lists of masked nodes ----------
extern "C" __global__ void __launch_bounds__(256)
k1_fill(const int* __restrict__ ei, const u64* __restrict__ bits,
        const int* __restrict__ nodeoff,
        int* __restrict__ fillcnt, int* __restrict__ adj, int E,
        const int* __restrict__ hdr)
{
  int e = blockIdx.x * 256 + threadIdx.x;
  if (e >= E) return;
  int is64 = hdr[2];
  int s = ldei(ei, e, is64);
  int d = ldei(ei, (long)E + e, is64);
  if (bit_test(bits, s)) {
    int os = nodeoff[s];
    if (os >= 0) { int p = atomicAdd(fillcnt + s, 1); adj[os + p] = d; }
  }
  if (bit_test(bits, d)) {
    int od = nodeoff[d];
    if (od >= 0) { int p = atomicAdd(fillcnt + d, 1); adj[od + p] = s; }
  }
}

// ---------- K3a: neighbor mean, wave per masked node, persistent ----------
// f32 fast path: lane = (neighbor slot g 0..3, float4 col fq 0..15);
// 4 rows fetched per wave-instr at 16 B/lane, shuffle-reduce across slots.
extern "C" __global__ void __launch_bounds__(256)
k3a_gather(const void* __restrict__ featv, const int* __restrict__ cnt,
           const int* __restrict__ nodeoff, const int* __restrict__ nlist,
           const int* __restrict__ adj, const int* __restrict__ hdr,
           float* __restrict__ out)
{
  const int lane = threadIdx.x & 63;
  const int q = __builtin_amdgcn_readfirstlane(threadIdx.x >> 6);
  const int dt = hdr[0];
  const int nmask = hdr[4];
  if (dt == 0) {
    const float4* f4 = (const float4*)featv;
    const int g = lane >> 4;       // neighbor slot
    const int fq = lane & 15;      // float4 column in row
    for (long b = (long)blockIdx.x * 4 + q; b < nmask; b += (long)gridDim.x * 4) {
      int node = nlist[b];
      int off = nodeoff[node];
      int dg = cnt[node];
      float4 acc = make_float4(0.f, 0.f, 0.f, 0.f);
      int j = g;
      for (; j + 4 < dg; j += 8) {
        int n0 = adj[off + j];
        int n1 = adj[off + j + 4];
        float4 v0 = f4[(long)n0 * 16 + fq];
        float4 v1 = f4[(long)n1 * 16 + fq];
        acc.x += v0.x + v1.x; acc.y += v0.y + v1.y;
        acc.z += v0.z + v1.z; acc.w += v0.w + v1.w;
      }
      if (j < dg) {
        int n0 = adj[off + j];
        float4 v0 = f4[(long)n0 * 16 + fq];
        acc.x += v0.x; acc.y += v0.y; acc.z += v0.z; acc.w += v0.w;
      }
      acc.x += __shfl_xor(acc.x, 16); acc.y += __shfl_xor(acc.y, 16);
      acc.z += __shfl_xor(acc.z, 16); acc.w += __shfl_xor(acc.w, 16);
      acc.x += __shfl_xor(acc.x, 32); acc.y += __shfl_xor(acc.y, 32);
      acc.z += __shfl_xor(acc.z, 32); acc.w += __shfl_xor(acc.w, 32);
      if (g == 0) {
        float inv = 1.f / (float)dg;
        float4 r = make_float4(acc.x * inv, acc.y * inv, acc.z * inv, acc.w * inv);
        *(float4*)(out + (long)node * 68 + fq * 4) = r;
      }
    }
  } else {
    // generic scalar path (bf16/f16 features)
    for (long b = (long)blockIdx.x * 4 + q; b < nmask; b += (long)gridDim.x * 4) {
      int node = nlist[b];
      int off = nodeoff[node];
      int dg = cnt[node];
      float acc = 0.f;
      int j = 0;
      for (; j + 4 <= dg; j += 4) {
        int n0 = adj[off + j + 0];
        int n1 = adj[off + j + 1];
        int n2 = adj[off + j + 2];
        int n3 = adj[off + j + 3];
        float v0 = ldf(featv, (long)n0 * 64 + lane, dt);
        float v1 = ldf(featv, (long)n1 * 64 + lane, dt);
        float v2 = ldf(featv, (long)n2 * 64 + lane, dt);
        float v3 = ldf(featv, (long)n3 * 64 + lane, dt);
        acc += ((v0 + v1) + (v2 + v3));
      }
      for (; j < dg; ++j)
        acc += ldf(featv, (long)adj[off + j] * 64 + lane, dt);
      out[(long)node * 68 + lane] = acc / (float)dg;
    }
  }
}

// ---------- K3b: batched MLP, NPB=16 nodes/block, SINGLE-buffered LDS weights ----
// Schedule per chunk: {sync; stage chunk into WS; sync; FMA over chunk}.
// Inner loops read only LDS: weight reads are 16-lane broadcast, 4 unique
// addrs/wave at banks {0,8,16,24} -> conflict-free. Staging is coalesced
// float4 with 4-16 loads in flight -> L2 latency no longer exposed per-k.
extern "C" __global__ void __launch_bounds__(256)
k3b_mlp(const void* __restrict__ featv, const int* __restrict__ nlist,
        const float* __restrict__ wf, const int* __restrict__ hdr,
        float* __restrict__ out)
{
  __shared__ float A[128 * LDW];
  __shared__ float B[128 * LDW];
  __shared__ float WS[4096];          // 16 KB weight slab
  __shared__ int sNode[NPB];
  const int tid = threadIdx.x;
  const int nmask = hdr[4];
  const int base = blockIdx.x * NPB;
  if (nmask == 0 || base >= nmask) return;
  const int dt = hdr[0];
  const int nl = tid & 15;
  const int jg = tid >> 4;            // 0..15

  if (tid < NPB) {
    int idx = base + tid;
    sNode[tid] = nlist[(idx < nmask) ? idx : (nmask - 1)];
  }
  __syncthreads();

  // stage ctx: A[f][nl], f<64 = node features, f=64..127 = neighbor mean (from k3a)
#pragma unroll
  for (int i = 0; i < 8; ++i) {
    int g = i * 256 + tid;
    int f = g & 127;
    int n = g >> 7;
    int node = sNode[n];
    float v = (f < 64) ? ldf(featv, (long)node * 64 + f, dt)
                       : out[(long)node * 68 + (f - 64)];
    A[f * LDW + n] = v;
  }

  // ---- L1: 128 -> 128, relu. 4 chunks of 32 k-rows (4096 floats each) ----
  {
    const int j0 = jg * 8;
    float a0 = wf[O_b1 + j0 + 0], a1 = wf[O_b1 + j0 + 1];
    float a2 = wf[O_b1 + j0 + 2], a3 = wf[O_b1 + j0 + 3];
    float a4 = wf[O_b1 + j0 + 4], a5 = wf[O_b1 + j0 + 5];
    float a6 = wf[O_b1 + j0 + 6], a7 = wf[O_b1 + j0 + 7];
    for (int c = 0; c < 4; ++c) {
      __syncthreads();                 // WS free (and ctx-stage done at c=0)
      {
        const float4* s4 = (const float4*)(wf + O_W1 + c * 4096);
        float4* d4 = (float4*)WS;
#pragma unroll
        for (int i = 0; i < 4; ++i) d4[tid + 256 * i] = s4[tid + 256 * i];
      }
      __syncthreads();                 // slab ready
#pragma unroll 4
      for (int k = 0; k < 32; ++k) {
        float x = A[(c * 32 + k) * LDW + nl];
        const float* w = WS + k * 128 + j0;
        float4 w0 = *(const float4*)(w);
        float4 w1 = *(const float4*)(w + 4);
        a0 = fmaf(x, w0.x, a0);
        a1 = fmaf(x, w0.y, a1);
        a2 = fmaf(x, w0.z, a2);
        a3 = fmaf(x, w0.w, a3);
        a4 = fmaf(x, w1.x, a4);
        a5 = fmaf(x, w1.y, a5);
        a6 = fmaf(x, w1.z, a6);
        a7 = fmaf(x, w1.w, a7);
      }
    }
    B[(j0 + 0) * LDW + nl] = fmaxf(a0, 0.f);
    B[(j0 + 1) * LDW + nl] = fmaxf(a1, 0.f);
    B[(j0 + 2) * LDW + nl] = fmaxf(a2, 0.f);
    B[(j0 + 3) * LDW + nl] = fmaxf(a3, 0.f);
    B[(j0 + 4) * LDW + nl] = fmaxf(a4, 0.f);
    B[(j0 + 5) * LDW + nl] = fmaxf(a5, 0.f);
    B[(j0 + 6) * LDW + nl] = fmaxf(a6, 0.f);
    B[(j0 + 7) * LDW + nl] = fmaxf(a7, 0.f);
  }

  // ---- L2: 128 -> 64, relu. 2 chunks of 64 k-rows (4096 floats each) ----
  {
    const int j0 = jg * 4;
    float a0 = wf[O_b2 + j0 + 0], a1 = wf[O_b2 + j0 + 1];
    float a2 = wf[O_b2 + j0 + 2], a3 = wf[O_b2 + j0 + 3];
    for (int c = 0; c < 2; ++c) {
      __syncthreads();                 // WS free + (c=0) B writes done
      {
        const float4* s4 = (const float4*)(wf + O_W2 + c * 4096);
        float4* d4 = (float4*)WS;
#pragma unroll
        for (int i = 0; i < 4; ++i) d4[tid + 256 * i] = s4[tid + 256 * i];
      }
      __syncthreads();
#pragma unroll 4
      for (int k = 0; k < 64; ++k) {
        float x = B[(c * 64 + k) * LDW + nl];
        float4 w = *(const float4*)(WS + k * 64 + j0);
        a0 = fmaf(x, w.x, a0);
        a1 = fmaf(x, w.y, a1);
        a2 = fmaf(x, w.z, a2);
        a3 = fmaf(x, w.w, a3);
      }
    }
    A[(j0 + 0) * LDW + nl] = fmaxf(a0, 0.f);
    A[(j0 + 1) * LDW + nl] = fmaxf(a1, 0.f);
    A[(j0 + 2) * LDW + nl] = fmaxf(a2, 0.f);
    A[(j0 + 3) * LDW + nl] = fmaxf(a3, 0.f);
  }

  // ---- L3: 64 -> 67 (no relu). 2 chunks of 32 k-rows (2144 floats each) ----
  {
    const int jq = jg;
    const bool has5 = (jq < 3);
    float a0 = 0.f, a1 = 0.f, a2 = 0.f, a3 = 0.f, a4 = 0.f;
    for (int c = 0; c < 2; ++c) {
      __syncthreads();                 // WS free + (c=0) A writes done
      {
        const float4* s4 = (const float4*)(wf + O_W3 + c * 2144);
        float4* d4 = (float4*)WS;
        for (int i = tid; i < 536; i += 256) d4[i] = s4[i];
      }
      __syncthreads();
#pragma unroll 4
      for (int k = 0; k < 32; ++k) {
        float x = A[(c * 32 + k) * LDW + nl];
        const float* w = WS + k * 67 + jq;
        float w4 = has5 ? w[64] : 0.f;  // max idx 31*67+2+64 = 2143 < 2144
        a0 = fmaf(x, w[0],  a0);
        a1 = fmaf(x, w[16], a1);
        a2 = fmaf(x, w[32], a2);
        a3 = fmaf(x, w[48], a3);
        a4 = fmaf(x, w4,    a4);
      }
    }
    B[(jq +  0) * LDW + nl] = wf[O_b3 + jq]      + a0;
    B[(jq + 16) * LDW + nl] = wf[O_b3 + jq + 16] + a1;
    B[(jq + 32) * LDW + nl] = wf[O_b3 + jq + 32] + a2;
    B[(jq + 48) * LDW + nl] = wf[O_b3 + jq + 48] + a3;
    if (has5)
      B[(jq + 64) * LDW + nl] = wf[O_b3 + jq + 64] + a4;
  }

  // ---- L4: gen[3..66] -> 32, relu. P1 = 2048 floats, one slab (scalar stage:
  //      O_P1 not 16B-aligned) ----
  {
    const int jq = jg;
    float a0 = wf[O_pb1 + jq], a1 = wf[O_pb1 + jq + 16];
    __syncthreads();                   // WS free + B writes done
    for (int i = tid; i < 2048; i += 256) WS[i] = wf[O_P1 + i];
    __syncthreads();
#pragma unroll 4
    for (int k = 0; k < 64; ++k) {
      float x = B[(3 + k) * LDW + nl];
      a0 = fmaf(x, WS[k * 32 + jq],      a0);
      a1 = fmaf(x, WS[k * 32 + jq + 16], a1);
    }
    A[(jq +  0) * LDW + nl] = fmaxf(a0, 0.f);
    A[(jq + 16) * LDW + nl] = fmaxf(a1, 0.f);
  }
  __syncthreads();

  // ---- L5: 32 -> sigmoid prob. wave 0: 4 partial lanes per node ----
  if (tid < 64) {
    const int part = tid >> 4;          // 0..3
    float p = 0.f;
#pragma unroll
    for (int kk = 0; kk < 8; ++kk) {
      int k = part * 8 + kk;
      p = fmaf(A[k * LDW + nl], wf[O_P2 + k], p);
    }
    p += __shfl_xor(p, 16);
    p += __shfl_xor(p, 32);
    if (part == 0) {
      float z = wf[O_pb2] + p;
      B[67 * LDW + nl] = 1.0f / (1.0f + expf(-z));
    }
  }
  __syncthreads();

  // store: 16 nodes x 68 channels, channel fastest -> coalesced 68-float runs
  for (int g = tid; g < NPB * 68; g += 256) {
    int n = g / 68;
    int c = g - n * 68;
    if (base + n < nmask) {
      int node = sNode[n];
      out[(long)node * 68 + c] = B[c * LDW + n];
    }
  }
}

extern "C" void kernel_launch(void* const* d_in, const int* in_sizes, int n_in,
                              void* d_out, int out_size, void* d_ws, size_t ws_size,
                              hipStream_t stream) {
  // ---- identify tensors by element count (fallback: documented order) ----
  int iF = 0, iO = 1, iE = 2;
  int iW1 = 3, ib1 = 4, iW2 = 5, ib2 = 6, iW3 = 7, ib3 = 8;
  int iP1 = 9, ipb1 = 10, iP2 = 11, ipb2 = 12;
  {
    int bigs[4]; int nb = 0;
    for (int i = 0; i < n_in && nb < 4; ++i)
      if (in_sizes[i] > 100000) bigs[nb++] = i;
    if (nb == 3) {
      int a = bigs[0], b = bigs[1], c = bigs[2];
      int mx = a, mn = a;
      if (in_sizes[b] > in_sizes[mx]) mx = b;
      if (in_sizes[c] > in_sizes[mx]) mx = c;
      if (in_sizes[b] < in_sizes[mn]) mn = b;
      if (in_sizes[c] < in_sizes[mn]) mn = c;
      iF = mx; iO = mn; iE = a + b + c - mx - mn;
      int t32[2]; int n32 = 0;
      int jW1=-1, jb1=-1, jW2=-1, jb2=-1, jW3=-1, jb3=-1, jP1=-1, jpb2=-1;
      for (int i = 0; i < n_in; ++i) {
        if (i == iF || i == iO || i == iE) continue;
        switch (in_sizes[i]) {
          case 16384: jW1 = i; break;
          case 128:   jb1 = i; break;
          case 8192:  jW2 = i; break;
          case 64:    jb2 = i; break;
          case 4288:  jW3 = i; break;
          case 67:    jb3 = i; break;
          case 2048:  jP1 = i; break;
          case 1:     jpb2 = i; break;
          case 32:    if (n32 < 2) t32[n32++] = i; break;
          default: break;
        }
      }
      if (jW1 >= 0 && jb1 >= 0 && jW2 >= 0 && jb2 >= 0 && jW3 >= 0 &&
          jb3 >= 0 && jP1 >= 0 && jpb2 >= 0 && n32 == 2) {
        iW1 = jW1; ib1 = jb1; iW2 = jW2; ib2 = jb2; iW3 = jW3; ib3 = jb3;
        iP1 = jP1; ipb2 = jpb2;
        if (t32[1] == t32[0] + 1) { ipb1 = t32[0]; iP2 = t32[1]; }
        else                      { iP2 = t32[0]; ipb1 = t32[1]; }
      }
    }
  }
  int N = (out_size % 68 == 0) ? (out_size / 68) : (in_sizes[iF] / 64);
  const int E = in_sizes[iE] / 2;
  const void* feat = d_in[iF];
  const void* ops  = d_in[iO];
  const int* ei    = (const int*)d_in[iE];

  // workspace: hdr | wf | bits | cnt | nodeoff | fillcnt | nlist | adj(2E)
  char* ws = (char*)d_ws;
  int* hdr = (int*)ws;
  size_t off = 256;
  float* wf = (float*)(ws + off);
  off += ((size_t)W_TOTAL * 4 + 255) & ~(size_t)255;
  u64* bits = (u64*)(ws + off);
  off += (((size_t)(N + 63) / 64) * 8 + 255) & ~(size_t)255;
  int* cnt = (int*)(ws + off);
  off += ((size_t)N * 4 + 255) & ~(size_t)255;
  int* nodeoff = (int*)(ws + off);
  off += ((size_t)N * 4 + 255) & ~(size_t)255;
  int* fillcnt = (int*)(ws + off);
  off += ((size_t)N * 4 + 255) & ~(size_t)255;
  int* nlist = (int*)(ws + off);
  off += ((size_t)N * 4 + 255) & ~(size_t)255;
  int* adj = (int*)(ws + off);

  hipMemsetAsync(hdr, 0, 256, stream);
  hipMemsetAsync(d_out, 0, (size_t)out_size * 4, stream);

  kall_detect<<<4, 64, 0, stream>>>((const u32*)feat, (const u32*)d_in[iW1],
                                    (const u32*)ops, (const u32*)ei, hdr);

  kw_conv<<<(W_TOTAL + 255) / 256, 256, 0, stream>>>(
      d_in[iW1], d_in[ib1], d_in[iW2], d_in[ib2], d_in[iW3], d_in[ib3],
      d_in[iP1], d_in[ipb1], d_in[iP2], d_in[ipb2], hdr, wf);
  k2a_cand<<<(N + 255) / 256, 256, 0, stream>>>(ops, hdr, bits, cnt, fillcnt, N);
  k1a_cnt<<<(E + 255) / 256, 256, 0, stream>>>(ei, bits, cnt, E, hdr);
  k2b_alloc<<<(N + 255) / 256, 256, 0, stream>>>(bits, cnt, hdr, nodeoff, nlist, N);
  k1_fill<<<(E + 255) / 256, 256, 0, stream>>>(ei, bits, nodeoff, fillcnt, adj, E, hdr);
  k3a_gather<<<2048, 256, 0, stream>>>(feat, cnt, nodeoff, nlist, adj, hdr,
                                       (float*)d_out);
  k3b_mlp<<<(N + NPB - 1) / NPB, 256, 0, stream>>>(feat, nlist, wf, hdr,
                                                   (float*)d_out);
}